// Round 5
// baseline (417.915 us; speedup 1.0000x reference)
//
#include <hip/hip_runtime.h>

// Problem constants (from reference setup_inputs):
//   B=16, T=4096 routing slots, D=512 embed dim, max_nodes=1024, max_edges=2048
#define NB 16
#define NT 4096
#define ND 512
#define ND4 128           // D / 4 floats per float4
#define MAX_NODES 1024
#define MAX_EDGES 2048
#define NODE_ROWS 2048    // max_nodes * 2 (repeat 2)
#define EDGE_ROWS 10240   // max_edges * 5 (repeat 5)
#define ROWS_NODE_TOT 32768u   // NB * NODE_ROWS
#define NODE_SLOTS 16384u      // NB * MAX_NODES
#define EDGE_SLOTS 32768u      // NB * MAX_EDGES
#define TOTAL_WAVES 49152u     // NODE_SLOTS + EDGE_SLOTS

typedef __attribute__((ext_vector_type(4))) float f4;

// ---------------------------------------------------------------------------
// Kernel 1: stable stream compaction via packed prefix scan.
// One block per batch row. 1024 threads x 4 elements (int4 load).
// packed counter: high 16 bits = #zeros, low 16 bits = #ones (max 4096 each,
// no cross-field carry possible).
// ---------------------------------------------------------------------------
__global__ __launch_bounds__(1024) void compact_kernel(
    const int* __restrict__ routing,
    int* __restrict__ node_pos,   // [NB][MAX_NODES]
    int* __restrict__ edge_pos)   // [NB][MAX_EDGES]
{
    const int b   = blockIdx.x;
    const int tid = threadIdx.x;           // 0..1023
    const int lane = tid & 63;
    const int wv   = tid >> 6;             // wave id, 0..15

    const int4 v = reinterpret_cast<const int4*>(routing + b * NT)[tid];
    const int e0 = v.x, e1 = v.y, e2 = v.z, e3 = v.w;

    // within-thread inclusive packed prefix over the 4 elements
    unsigned inc0 = ((e0 == 0) ? 0x10000u : 0u) | ((e0 == 1) ? 1u : 0u);
    unsigned inc1 = ((e1 == 0) ? 0x10000u : 0u) | ((e1 == 1) ? 1u : 0u);
    unsigned inc2 = ((e2 == 0) ? 0x10000u : 0u) | ((e2 == 1) ? 1u : 0u);
    unsigned inc3 = ((e3 == 0) ? 0x10000u : 0u) | ((e3 == 1) ? 1u : 0u);
    unsigned p0 = inc0;
    unsigned p1 = p0 + inc1;
    unsigned p2 = p1 + inc2;
    unsigned p3 = p2 + inc3;
    const unsigned my_sum = p3;

    // wave-64 inclusive scan of per-thread sums
    unsigned x = my_sum;
    #pragma unroll
    for (int off = 1; off < 64; off <<= 1) {
        unsigned y = __shfl_up(x, off, 64);
        if (lane >= off) x += y;
    }

    __shared__ unsigned wave_sums[16];
    if (lane == 63) wave_sums[wv] = x;

    // init the output slots to -1 while the scan data settles
    node_pos[b * MAX_NODES + tid] = -1;
    edge_pos[b * MAX_EDGES + 2 * tid + 0] = -1;
    edge_pos[b * MAX_EDGES + 2 * tid + 1] = -1;
    __syncthreads();

    unsigned offset = 0;
    for (int i = 0; i < wv; ++i) offset += wave_sums[i];

    // exclusive packed prefix at this thread's first element
    const unsigned base = offset + x - my_sum;

    const unsigned ex0 = base;
    const unsigned ex1 = base + p0;
    const unsigned ex2 = base + p1;
    const unsigned ex3 = base + p2;

    const int t0 = tid * 4;
    #pragma unroll 4
    for (int i = 0; i < 4; ++i) {
        const int      e  = (i == 0) ? e0 : (i == 1) ? e1 : (i == 2) ? e2 : e3;
        const unsigned ex = (i == 0) ? ex0 : (i == 1) ? ex1 : (i == 2) ? ex2 : ex3;
        if (e == 0) {
            const unsigned rank = ex >> 16;
            if (rank < MAX_NODES) node_pos[b * MAX_NODES + rank] = t0 + i;
        } else if (e == 1) {
            const unsigned rank = ex & 0xFFFFu;
            if (rank < MAX_EDGES) edge_pos[b * MAX_EDGES + rank] = t0 + i;
        }
    }
}

// ---------------------------------------------------------------------------
// Kernel 2: dedup-read scatter. One wave per TOKEN SLOT. The wave loads its
// 2 KB pe row once (2 float4 / lane) and stores it to all repeat rows:
// node slot -> 2 consecutive rows (4 KB), edge slot -> 5 rows (10 KB).
// Round-5 single-variable change: PLAIN stores instead of nontemporal.
// A/B evidence: harness fill kernel (plain stores) sustains 6.2 TB/s on this
// very buffer; our nt-store kernels plateau at ~3 TB/s effective. nt bypasses
// L2's full-line writeback path — suspected ~2x write-efficiency penalty.
// ---------------------------------------------------------------------------
__global__ __launch_bounds__(256) void scatter_rows_kernel(
    const f4* __restrict__ pe,            // [4096][ND4]
    const int* __restrict__ node_pos,     // [NODE_SLOTS] = [NB][MAX_NODES]
    const int* __restrict__ edge_pos,     // [EDGE_SLOTS] = [NB][MAX_EDGES]
    f4* __restrict__ out)                 // [ROWS_TOTAL][ND4]
{
    const unsigned gid  = blockIdx.x * 256u + threadIdx.x;
    const unsigned wave = gid >> 6;        // 0..TOTAL_WAVES-1
    const unsigned t    = gid & 63u;

    if (wave < NODE_SLOTS) {
        const unsigned b = wave >> 10;         // / MAX_NODES
        const unsigned j = wave & 1023u;
        const int tok = node_pos[wave];        // [b][j] contiguous
        const int src = tok < 0 ? 0 : tok;
        const f4* srcp = pe + (size_t)src * ND4;
        const f4 v0 = srcp[t];
        const f4 v1 = srcp[t + 64];
        // node_pe rows 2j, 2j+1 of batch b
        f4* dst = out + ((size_t)b * NODE_ROWS + 2u * j) * ND4;
        dst[t]            = v0;
        dst[t + 64]       = v1;
        dst[128 + t]      = v0;
        dst[128 + t + 64] = v1;
    } else {
        const unsigned s = wave - NODE_SLOTS;  // 0..EDGE_SLOTS-1
        const unsigned b = s >> 11;            // / MAX_EDGES
        const unsigned j = s & 2047u;
        const int tok = edge_pos[s];           // [b][j] contiguous
        const int src = tok < 0 ? 0 : tok;
        const f4* srcp = pe + (size_t)src * ND4;
        const f4 v0 = srcp[t];
        const f4 v1 = srcp[t + 64];
        // edge_pe rows 5j..5j+4 of batch b
        f4* dst = out + (ROWS_NODE_TOT + (size_t)b * EDGE_ROWS + 5u * j) * ND4;
        #pragma unroll
        for (unsigned r = 0; r < 5; ++r) {
            dst[r * 128u + t]      = v0;
            dst[r * 128u + t + 64] = v1;
        }
    }
}

extern "C" void kernel_launch(void* const* d_in, const int* in_sizes, int n_in,
                              void* d_out, int out_size, void* d_ws, size_t ws_size,
                              hipStream_t stream) {
    // inputs (setup_inputs order): routing [16,4096] i32, max_nodes (1024),
    // max_edges (2048), pos_embed [4096,512] f32
    const int*   routing = (const int*)d_in[0];
    const float* pe      = (const float*)d_in[3];

    int* node_pos = (int*)d_ws;                          // 16*1024 ints = 64 KB
    int* edge_pos = node_pos + NB * MAX_NODES;           // 16*2048 ints = 128 KB

    compact_kernel<<<NB, 1024, 0, stream>>>(routing, node_pos, edge_pos);

    const unsigned total_threads = TOTAL_WAVES * 64u;    // 3,145,728
    scatter_rows_kernel<<<total_threads / 256, 256, 0, stream>>>(
        (const f4*)pe, node_pos, edge_pos, (f4*)d_out);
}

// Round 6
// 406.763 us; speedup vs baseline: 1.0274x; 1.0274x over previous
//
#include <hip/hip_runtime.h>

// Problem constants (from reference setup_inputs):
//   B=16, T=4096 routing slots, D=512 embed dim, max_nodes=1024, max_edges=2048
#define NB 16
#define NT 4096
#define ND4 128            // D/4 floats per float4
#define MAX_NODES 1024
#define MAX_EDGES 2048
#define NODE_ROWS 2048     // max_nodes * 2
#define EDGE_ROWS 10240    // max_edges * 5
#define ROWS_NODE_TOT 32768u   // NB * NODE_ROWS
#define SUBS 32            // blocks per batch
#define NBLK (NB * SUBS)   // 512 blocks
#define NODE_ROWS_PER_BLK 64u    // NODE_ROWS / SUBS
#define EDGE_ROWS_PER_BLK 320u   // EDGE_ROWS / SUBS

typedef __attribute__((ext_vector_type(4))) float f4;

// ---------------------------------------------------------------------------
// Single fused kernel. 512 blocks x 1024 threads; block = (batch b, slice sub).
// Phase 1: block-local stable compaction of routing row b via packed prefix
//   scan (hi16 = #zeros, lo16 = #ones), ranks scattered into LDS. Duplicated
//   SUBS x per batch -- trivially cheap (16 KB reads + ~30 VALU per thread).
// Phase 2: per-row gather (r3 structure, best measured): each wave handles one
//   output row per iteration: tok from LDS (broadcast), 2 float4 loads from
//   pe, 2 nontemporal float4 stores (2 KB contiguous).
// Removes: compact dispatch, one graph-node boundary, all d_ws traffic.
// ---------------------------------------------------------------------------
__global__ __launch_bounds__(1024) void fused_pe_kernel(
    const int* __restrict__ routing,   // [NB][NT]
    const f4*  __restrict__ pe,        // [4096][ND4]
    f4*        __restrict__ out)       // [ROWS_TOTAL][ND4]
{
    const unsigned blk = blockIdx.x;
    const unsigned b   = blk >> 5;          // / SUBS
    const unsigned sub = blk & 31u;
    const int tid  = threadIdx.x;           // 0..1023
    const int lane = tid & 63;
    const int wv   = tid >> 6;              // 0..15

    __shared__ int      node_lds[MAX_NODES];
    __shared__ int      edge_lds[MAX_EDGES];
    __shared__ unsigned wave_sums[16];

    // ---- phase 1: packed prefix scan (same math as the proven compact) ----
    const int4 v = reinterpret_cast<const int4*>(routing + b * NT)[tid];
    const int e0 = v.x, e1 = v.y, e2 = v.z, e3 = v.w;

    unsigned inc0 = ((e0 == 0) ? 0x10000u : 0u) | ((e0 == 1) ? 1u : 0u);
    unsigned inc1 = ((e1 == 0) ? 0x10000u : 0u) | ((e1 == 1) ? 1u : 0u);
    unsigned inc2 = ((e2 == 0) ? 0x10000u : 0u) | ((e2 == 1) ? 1u : 0u);
    unsigned inc3 = ((e3 == 0) ? 0x10000u : 0u) | ((e3 == 1) ? 1u : 0u);
    unsigned p0 = inc0;
    unsigned p1 = p0 + inc1;
    unsigned p2 = p1 + inc2;
    unsigned p3 = p2 + inc3;
    const unsigned my_sum = p3;

    unsigned x = my_sum;
    #pragma unroll
    for (int off = 1; off < 64; off <<= 1) {
        unsigned y = __shfl_up(x, off, 64);
        if (lane >= off) x += y;
    }
    if (lane == 63) wave_sums[wv] = x;

    node_lds[tid]             = -1;
    edge_lds[2 * tid + 0]     = -1;
    edge_lds[2 * tid + 1]     = -1;
    __syncthreads();

    unsigned offset = 0;
    for (int i = 0; i < wv; ++i) offset += wave_sums[i];
    const unsigned base = offset + x - my_sum;

    const unsigned ex0 = base;
    const unsigned ex1 = base + p0;
    const unsigned ex2 = base + p1;
    const unsigned ex3 = base + p2;

    const int t0 = tid * 4;
    #pragma unroll 4
    for (int i = 0; i < 4; ++i) {
        const int      e  = (i == 0) ? e0 : (i == 1) ? e1 : (i == 2) ? e2 : e3;
        const unsigned ex = (i == 0) ? ex0 : (i == 1) ? ex1 : (i == 2) ? ex2 : ex3;
        if (e == 0) {
            const unsigned rank = ex >> 16;
            if (rank < MAX_NODES) node_lds[rank] = t0 + i;
        } else if (e == 1) {
            const unsigned rank = ex & 0xFFFFu;
            if (rank < MAX_EDGES) edge_lds[rank] = t0 + i;
        }
    }
    __syncthreads();

    // ---- phase 2: per-row gather/stores (r3 structure, nt stores) ----
    // node rows of this block: [sub*64, sub*64+64) within batch b
    {
        f4* nbase = out + (size_t)b * NODE_ROWS * ND4;
        #pragma unroll 2
        for (unsigned r = wv; r < NODE_ROWS_PER_BLK; r += 16) {
            const unsigned row = sub * NODE_ROWS_PER_BLK + r;
            const int tok = node_lds[row >> 1];
            const int src = tok < 0 ? 0 : tok;
            const f4* s = pe + (size_t)src * ND4;
            const f4 a0 = s[lane];
            const f4 a1 = s[lane + 64];
            f4* d = nbase + (size_t)row * ND4;
            __builtin_nontemporal_store(a0, d + lane);
            __builtin_nontemporal_store(a1, d + lane + 64);
        }
    }
    // edge rows of this block: [sub*320, sub*320+320) within batch b
    {
        f4* ebase = out + ((size_t)ROWS_NODE_TOT + (size_t)b * EDGE_ROWS) * ND4;
        #pragma unroll 4
        for (unsigned r = wv; r < EDGE_ROWS_PER_BLK; r += 16) {
            const unsigned row = sub * EDGE_ROWS_PER_BLK + r;
            const int tok = edge_lds[row / 5u];
            const int src = tok < 0 ? 0 : tok;
            const f4* s = pe + (size_t)src * ND4;
            const f4 a0 = s[lane];
            const f4 a1 = s[lane + 64];
            f4* d = ebase + (size_t)row * ND4;
            __builtin_nontemporal_store(a0, d + lane);
            __builtin_nontemporal_store(a1, d + lane + 64);
        }
    }
}

extern "C" void kernel_launch(void* const* d_in, const int* in_sizes, int n_in,
                              void* d_out, int out_size, void* d_ws, size_t ws_size,
                              hipStream_t stream) {
    // inputs (setup_inputs order): routing [16,4096] i32, max_nodes (1024),
    // max_edges (2048), pos_embed [4096,512] f32
    const int*   routing = (const int*)d_in[0];
    const float* pe      = (const float*)d_in[3];

    fused_pe_kernel<<<NBLK, 1024, 0, stream>>>(
        routing, (const f4*)pe, (f4*)d_out);
}